// Round 9
// baseline (60.354 us; speedup 1.0000x reference)
//
#include <hip/hip_runtime.h>
#include <stdint.h>

#define NTOK 8192
#define NCOL 4096     // DIM == VOCAB
#define RANK 256
#define TPB  256      // tokens per block (4 waves x 64 tokens)
#define CPB  256      // cols per block

typedef __attribute__((ext_vector_type(8))) short bf16x8;
typedef __attribute__((ext_vector_type(4))) float f32x4;

__device__ __forceinline__ unsigned short f2bf(float f) {
    unsigned int u = __float_as_uint(f);
    u += 0x7fffu + ((u >> 16) & 1u);   // RNE
    return (unsigned short)(u >> 16);
}

// ---- combined pre-pass ----
// blocks [0, 1024): A fp32 [4096][256] -> bf16 row-major (Abf, 2 MiB)
// blocks [1024, 1536): B fp32 [256][4096] -> bf16 MFMA-B-fragment order
//   frag layout: flat uint4 index = (ct*8 + ks)*64 + lane, 8 bf16 each:
//     element j = B[ks*32 + (lane>>4)*8 + j][ct*16 + (lane&15)]
__global__ __launch_bounds__(256) void prep_kernel(
    const float* __restrict__ A, const float* __restrict__ B,
    unsigned short* __restrict__ Abf, unsigned short* __restrict__ Bfrag)
{
    if (blockIdx.x < 1024) {
        int i = blockIdx.x * 256 + threadIdx.x;
        float4 v = reinterpret_cast<const float4*>(A)[i];
        ushort4 o;
        o.x = f2bf(v.x); o.y = f2bf(v.y); o.z = f2bf(v.z); o.w = f2bf(v.w);
        reinterpret_cast<ushort4*>(Abf)[i] = o;
    } else {
        int gt = (blockIdx.x - 1024) * 256 + threadIdx.x;
        int ct = gt >> 9;
        int rem = gt & 511;
        int ks = rem >> 6;
        int ln = rem & 63;
        int col = ct * 16 + (ln & 15);
        int kb  = ks * 32 + ((ln >> 4) << 3);
        unsigned short pk[8];
        #pragma unroll
        for (int j = 0; j < 8; ++j)
            pk[j] = f2bf(B[(size_t)(kb + j) * NCOL + col]);
        uint4 o;
        o.x = (unsigned)pk[0] | ((unsigned)pk[1] << 16);
        o.y = (unsigned)pk[2] | ((unsigned)pk[3] << 16);
        o.z = (unsigned)pk[4] | ((unsigned)pk[5] << 16);
        o.w = (unsigned)pk[6] | ((unsigned)pk[7] << 16);
        reinterpret_cast<uint4*>(Bfrag)[gt] = o;
    }
}

// ---- main: fused gather + LoRA GEMM + W add + mask ----
// M=64 tokens/wave (4 MFMA token-groups): every B-fragment load feeds 4
// accumulator chains -> B L1 traffic per output byte is 2:1 (was 4:1 in r8).
__global__ __launch_bounds__(256) void emb_lora_mfma(
    const int* __restrict__ x,
    const int* __restrict__ mask,
    const float* __restrict__ W,
    const unsigned short* __restrict__ Abf,
    const unsigned short* __restrict__ Bfrag,
    float* __restrict__ out)
{
    __shared__ int s_idx[TPB];
    __shared__ int s_msk[TPB];

    const int tid  = threadIdx.x;
    const int lane = tid & 63;
    const int wave = tid >> 6;        // wave owns tokens [wave*64, wave*64+64)
    const int tok0 = blockIdx.x * TPB;
    const int col0 = blockIdx.y * CPB;

    s_idx[tid] = x[tok0 + tid];
    s_msk[tid] = mask[tok0 + tid];
    __syncthreads();

    // A fragments, 4 token groups (A-operand row = lane&15)
    bf16x8 af[4][8];
    #pragma unroll
    for (int g = 0; g < 4; ++g) {
        const int ar = s_idx[wave * 64 + g * 16 + (lane & 15)];
        const unsigned short* ap = Abf + (size_t)ar * RANK + ((lane >> 4) << 3);
        #pragma unroll
        for (int s = 0; s < 8; ++s)
            af[g][s] = *reinterpret_cast<const bf16x8*>(ap + s * 32);
    }

    // per-thread epilogue state. Group g covers rows wave*64+g*16+(lane>>4)*4+r.
    // Masks packed into one bitmask; out offsets derived from 4 bases.
    const int colb = col0 + (lane & 15);
    unsigned mbits = 0;
    unsigned woff[4][4];
    unsigned obase[4];
    #pragma unroll
    for (int g = 0; g < 4; ++g) {
        const int rb = wave * 64 + g * 16 + ((lane >> 4) << 2);
        obase[g] = (unsigned)(tok0 + rb) * NCOL + colb;
        #pragma unroll
        for (int r = 0; r < 4; ++r) {
            mbits |= (s_msk[rb + r] ? 1u : 0u) << (g * 4 + r);
            woff[g][r] = (unsigned)s_idx[rb + r] * NCOL + colb;
        }
    }

    // all 4 waves share these 16 col-tiles (B frags L1-resident after wave 0)
    const uint4* bcol = reinterpret_cast<const uint4*>(Bfrag)
                        + (size_t)(blockIdx.y * 16) * 512 + lane;

    // W prefetch: 3-slot rotating ring, 2-tile lead. Exec-masked `if` loads
    // (NOT ternary — r3 lesson: speculation doubled FETCH_SIZE).
    float wv[3][4][4];
    #pragma unroll
    for (int p = 0; p < 2; ++p) {
        #pragma unroll
        for (int g = 0; g < 4; ++g) {
            #pragma unroll
            for (int r = 0; r < 4; ++r) {
                float v = 0.0f;
                if (!((mbits >> (g * 4 + r)) & 1u)) v = W[woff[g][r] + p * 16];
                wv[p][g][r] = v;
            }
        }
    }

#define TILE_BODY(T, PF)                                                  \
    {                                                                     \
        const int t_ = (T);                                               \
        uint4 bb[4];                                                      \
        _Pragma("unroll")                                                 \
        for (int s = 0; s < 4; ++s)                                       \
            bb[s] = bcol[t_ * 512 + s * 64];                              \
        if (PF) {                                                         \
            _Pragma("unroll")                                             \
            for (int g = 0; g < 4; ++g) {                                 \
                _Pragma("unroll")                                         \
                for (int r = 0; r < 4; ++r) {                             \
                    float v = 0.0f;                                       \
                    if (!((mbits >> (g * 4 + r)) & 1u))                   \
                        v = W[woff[g][r] + (t_ + 2) * 16];                \
                    wv[(T + 2) % 3][g][r] = v;                            \
                }                                                         \
            }                                                             \
        }                                                                 \
        f32x4 acc[4];                                                     \
        _Pragma("unroll")                                                 \
        for (int g = 0; g < 4; ++g) acc[g] = (f32x4){0.f, 0.f, 0.f, 0.f}; \
        _Pragma("unroll")                                                 \
        for (int s = 0; s < 4; ++s) {                                     \
            bf16x8 b = __builtin_bit_cast(bf16x8, bb[s]);                 \
            _Pragma("unroll")                                             \
            for (int g = 0; g < 4; ++g)                                   \
                acc[g] = __builtin_amdgcn_mfma_f32_16x16x32_bf16(         \
                    af[g][s], b, acc[g], 0, 0, 0);                        \
        }                                                                 \
        _Pragma("unroll")                                                 \
        for (int s = 0; s < 4; ++s)                                       \
            bb[s] = bcol[t_ * 512 + (s + 4) * 64];                        \
        _Pragma("unroll")                                                 \
        for (int s = 0; s < 4; ++s) {                                     \
            bf16x8 b = __builtin_bit_cast(bf16x8, bb[s]);                 \
            _Pragma("unroll")                                             \
            for (int g = 0; g < 4; ++g)                                   \
                acc[g] = __builtin_amdgcn_mfma_f32_16x16x32_bf16(         \
                    af[g][s + 4], b, acc[g], 0, 0, 0);                    \
        }                                                                 \
        _Pragma("unroll")                                                 \
        for (int g = 0; g < 4; ++g) {                                     \
            _Pragma("unroll")                                             \
            for (int r = 0; r < 4; ++r) {                                 \
                float v = 0.0f;                                           \
                if (!((mbits >> (g * 4 + r)) & 1u))                       \
                    v = acc[g][r] + wv[(T) % 3][g][r];                    \
                out[obase[g] + r * NCOL + t_ * 16] = v;                   \
            }                                                             \
        }                                                                 \
    }

    TILE_BODY(0, 1);  TILE_BODY(1, 1);  TILE_BODY(2, 1);  TILE_BODY(3, 1);
    TILE_BODY(4, 1);  TILE_BODY(5, 1);  TILE_BODY(6, 1);  TILE_BODY(7, 1);
    TILE_BODY(8, 1);  TILE_BODY(9, 1);  TILE_BODY(10, 1); TILE_BODY(11, 1);
    TILE_BODY(12, 1); TILE_BODY(13, 1);
    // peeled tail: no prefetch (avoids OOB reads past the block's col range)
    TILE_BODY(14, 0); TILE_BODY(15, 0);
#undef TILE_BODY
}

extern "C" void kernel_launch(void* const* d_in, const int* in_sizes, int n_in,
                              void* d_out, int out_size, void* d_ws, size_t ws_size,
                              hipStream_t stream) {
    (void)in_sizes; (void)n_in; (void)out_size; (void)ws_size;

    const int*   x    = (const int*)d_in[0];
    const int*   mask = (const int*)d_in[1];
    const float* W    = (const float*)d_in[2];
    const float* A    = (const float*)d_in[3];
    const float* B    = (const float*)d_in[4];
    float*       out  = (float*)d_out;

    unsigned short* Abf   = (unsigned short*)d_ws;                       // 2 MiB
    unsigned short* Bfrag = (unsigned short*)((char*)d_ws + (2u << 20)); // 2 MiB

    prep_kernel<<<dim3(1536), dim3(256), 0, stream>>>(A, B, Abf, Bfrag);

    dim3 grid(NTOK / TPB, NCOL / CPB);   // (32, 16) = 512 blocks
    emb_lora_mfma<<<grid, dim3(256), 0, stream>>>(x, mask, W, Abf, Bfrag, out);
}